// Round 1
// baseline (206.612 us; speedup 1.0000x reference)
//
#include <hip/hip_runtime.h>
#include <hip/hip_bf16.h>

#define NB 8
#define SEQ 2048
#define DM 1024
#define AD 64

typedef __attribute__((ext_vector_type(8))) short short8;
typedef __attribute__((ext_vector_type(4))) float f32x4;

static __device__ __forceinline__ unsigned short f2bf(float f) {
    unsigned int u = __float_as_uint(f);
    u += 0x7FFFu + ((u >> 16) & 1u);
    return (unsigned short)(u >> 16);
}

static __device__ __forceinline__ f32x4 mfma16(short8 a, short8 b, f32x4 c) {
    return __builtin_amdgcn_mfma_f32_16x16x32_bf16(a, b, c, 0, 0, 0);
}

// ---------------------------------------------------------------------------
// Kernel 0: transpose + convert W (fp32 [1024][64]) -> wT bf16 [3][64][1024]
// grid (16, 3), block 256
// ---------------------------------------------------------------------------
__global__ __launch_bounds__(256) void wT_kernel(
    const float* __restrict__ Wq, const float* __restrict__ Wk,
    const float* __restrict__ Wv, unsigned short* __restrict__ wT) {
    int p = blockIdx.y;
    int k0 = blockIdx.x * 64;
    const float* W = (p == 0) ? Wq : (p == 1) ? Wk : Wv;
    __shared__ unsigned short tl[64][72];
    int t = threadIdx.x;
    int c = t & 63;          // contiguous dim of W row (a)
    int r0 = t >> 6;
    for (int i = 0; i < 16; i++) {
        int k = r0 + i * 4;
        tl[c][k] = f2bf(W[(size_t)(k0 + k) * AD + c]);  // tl[a][k]
    }
    __syncthreads();
    for (int i = 0; i < 16; i++) {
        int a = r0 + i * 4;
        wT[((size_t)p * AD + a) * DM + k0 + c] = tl[a][c];
    }
}

// ---------------------------------------------------------------------------
// Kernel 1: projection X[16384][1024] @ W[1024][64] + b -> bf16
//   p=0 -> q_bf [row][64], p=1 -> k_bf [row][64], p=2 -> vT [b][64][2048]
// grid (256 row-tiles, 3), block 256 (4 waves; wave w owns rows w*16..w*16+15)
// ---------------------------------------------------------------------------
__global__ __launch_bounds__(256) void proj_kernel(
    const float* __restrict__ q_in, const float* __restrict__ k_in,
    const float* __restrict__ v_in, const float* __restrict__ bq,
    const float* __restrict__ bk, const float* __restrict__ bv,
    const unsigned short* __restrict__ wT,
    unsigned short* __restrict__ q_out, unsigned short* __restrict__ k_out,
    unsigned short* __restrict__ vT_out) {
    int p = blockIdx.y;
    int rbase = blockIdx.x * 64;
    const float* X = (p == 0) ? q_in : (p == 1) ? k_in : v_in;
    const float* bias = (p == 0) ? bq : (p == 1) ? bk : bv;
    const unsigned short* wTp = wT + (size_t)p * AD * DM;

    __shared__ unsigned short x_lds[64][72];  // bf16 input tile [row][k], pad 8

    int t = threadIdx.x;
    int lane = t & 63;
    int w = t >> 6;
    int arow = lane & 15;   // A-frag row / B-frag col
    int agrp = lane >> 4;   // k-group

    f32x4 acc[4];
#pragma unroll
    for (int ct = 0; ct < 4; ct++) acc[ct] = (f32x4){0.f, 0.f, 0.f, 0.f};

    int stage_c4 = (t & 15) * 4;  // float col within tile
    int stage_r0 = t >> 4;        // 0..15

    for (int ks = 0; ks < 16; ++ks) {
        int kbase = ks * 64;
        // stage fp32 -> bf16 LDS tile [64][64]
#pragma unroll
        for (int i = 0; i < 4; i++) {
            int row = stage_r0 + 16 * i;
            float4 xv = *reinterpret_cast<const float4*>(
                &X[(size_t)(rbase + row) * DM + kbase + stage_c4]);
            unsigned int lo = (unsigned)f2bf(xv.x) | ((unsigned)f2bf(xv.y) << 16);
            unsigned int hi = (unsigned)f2bf(xv.z) | ((unsigned)f2bf(xv.w) << 16);
            uint2 pk; pk.x = lo; pk.y = hi;
            *reinterpret_cast<uint2*>(&x_lds[row][stage_c4]) = pk;
        }
        __syncthreads();
        // MFMA: wave rows w*16..+16, all 64 output cols
        short8 af0 = *reinterpret_cast<const short8*>(&x_lds[w * 16 + arow][agrp * 8]);
        short8 af1 = *reinterpret_cast<const short8*>(&x_lds[w * 16 + arow][32 + agrp * 8]);
#pragma unroll
        for (int ct = 0; ct < 4; ct++) {
            const unsigned short* wr = wTp + (size_t)(ct * 16 + arow) * DM + kbase;
            short8 bf0 = *reinterpret_cast<const short8*>(wr + agrp * 8);
            short8 bf1 = *reinterpret_cast<const short8*>(wr + 32 + agrp * 8);
            acc[ct] = mfma16(af0, bf0, acc[ct]);
            acc[ct] = mfma16(af1, bf1, acc[ct]);
        }
        __syncthreads();
    }

    if (p < 2) {
        unsigned short* outp = (p == 0) ? q_out : k_out;
#pragma unroll
        for (int ct = 0; ct < 4; ct++) {
            int a = ct * 16 + arow;
            float bv_ = bias[a];
#pragma unroll
            for (int r = 0; r < 4; r++) {
                int row = rbase + w * 16 + agrp * 4 + r;
                outp[(size_t)row * AD + a] = f2bf(acc[ct][r] + bv_);
            }
        }
    } else {
        // transpose tile via LDS, then write vT[b][a][s]
#pragma unroll
        for (int ct = 0; ct < 4; ct++) {
            int a = ct * 16 + arow;
            float bv_ = bias[a];
#pragma unroll
            for (int r = 0; r < 4; r++) {
                int row = w * 16 + agrp * 4 + r;
                x_lds[a][row] = f2bf(acc[ct][r] + bv_);
            }
        }
        __syncthreads();
        int bidx = rbase >> 11;       // / 2048
        int sbase = rbase & 2047;
        int rr = t & 63;
        for (int i = 0; i < 16; i++) {
            int a = (t >> 6) + i * 4;
            vT_out[((size_t)bidx * AD + a) * SEQ + sbase + rr] = x_lds[a][rr];
        }
    }
}

// ---------------------------------------------------------------------------
// Kernel 2: attention. grid (128 q-tiles, 8 batches), block 256 (4 waves).
// Wave w owns keys [w*512, (w+1)*512).
// ---------------------------------------------------------------------------
union ScoreCtx {
    float s[16][2049];     // score / exp tile (padded: conflict-free)
    float ctx[4][16][68];  // per-wave context partials (reuse after scores dead)
};

__global__ __launch_bounds__(256) void attn_kernel(
    const unsigned short* __restrict__ qb, const unsigned short* __restrict__ kb,
    const unsigned short* __restrict__ vT, float* __restrict__ ctx_out,
    float* __restrict__ attn_out) {
    int b = blockIdx.y;
    int qt = blockIdx.x;
    int qbase = qt * 16;

    __shared__ ScoreCtx u;
    __shared__ unsigned short p_lds[4][16][136];  // per-wave bf16 P chunk
    __shared__ float rsum_lds[16];

    int t = threadIdx.x;
    int lane = t & 63;
    int w = t >> 6;
    int arow = lane & 15;
    int agrp = lane >> 4;

    // ---- Phase 1: scores = (Q @ K^T) / 32 into LDS ----
    const unsigned short* qrow = qb + ((size_t)b * SEQ + qbase) * AD;
    short8 qf0 = *reinterpret_cast<const short8*>(qrow + (size_t)arow * AD + agrp * 8);
    short8 qf1 = *reinterpret_cast<const short8*>(qrow + (size_t)arow * AD + 32 + agrp * 8);
    const unsigned short* kbp = kb + (size_t)b * SEQ * AD;
    for (int kt = 0; kt < 32; ++kt) {
        int key0 = w * 512 + kt * 16;
        const unsigned short* krow = kbp + (size_t)(key0 + arow) * AD;
        short8 kf0 = *reinterpret_cast<const short8*>(krow + agrp * 8);
        short8 kf1 = *reinterpret_cast<const short8*>(krow + 32 + agrp * 8);
        f32x4 acc = (f32x4){0.f, 0.f, 0.f, 0.f};
        acc = mfma16(qf0, kf0, acc);
        acc = mfma16(qf1, kf1, acc);
#pragma unroll
        for (int r = 0; r < 4; r++)
            u.s[agrp * 4 + r][key0 + arow] = acc[r] * 0.03125f;
    }
    __syncthreads();

    // ---- Phase 2: softmax stats (row t>>4 owned by 16-lane group t&15) ----
    {
        int srow = t >> 4;
        int sl = t & 15;
        float m = -1e30f;
        for (int c = sl; c < SEQ; c += 16) m = fmaxf(m, u.s[srow][c]);
#pragma unroll
        for (int off = 8; off; off >>= 1) m = fmaxf(m, __shfl_xor(m, off, 16));
        float sum = 0.f;
        for (int c = sl; c < SEQ; c += 16) {
            float e = __expf(u.s[srow][c] - m);
            u.s[srow][c] = e;
            sum += e;
        }
#pragma unroll
        for (int off = 8; off; off >>= 1) sum += __shfl_xor(sum, off, 16);
        if (sl == 0) rsum_lds[srow] = 1.0f / sum;
    }
    __syncthreads();

    // ---- Phase 3: normalize -> write attn + bf16 P -> PV MFMA ----
    float* attn_b = attn_out + ((size_t)b * SEQ + qbase) * SEQ;
    const unsigned short* vTb = vT + (size_t)b * AD * SEQ;
    f32x4 cacc[4];
#pragma unroll
    for (int ct = 0; ct < 4; ct++) cacc[ct] = (f32x4){0.f, 0.f, 0.f, 0.f};

    for (int cc = 0; cc < 4; ++cc) {
        int key0 = w * 512 + cc * 128;
#pragma unroll
        for (int r = 0; r < 16; r++) {
            float rs = rsum_lds[r];
#pragma unroll
            for (int i = 0; i < 2; i++) {
                int c = lane + i * 64;
                float e = u.s[r][key0 + c] * rs;
                attn_b[(size_t)r * SEQ + key0 + c] = e;
                p_lds[w][r][c] = f2bf(e);
            }
        }
        __syncthreads();
#pragma unroll
        for (int ks = 0; ks < 4; ++ks) {
            short8 pf = *reinterpret_cast<const short8*>(&p_lds[w][arow][ks * 32 + agrp * 8]);
#pragma unroll
            for (int ct = 0; ct < 4; ct++) {
                const unsigned short* vrow =
                    vTb + (size_t)(ct * 16 + arow) * SEQ + key0 + ks * 32 + agrp * 8;
                cacc[ct] = mfma16(pf, *reinterpret_cast<const short8*>(vrow), cacc[ct]);
            }
        }
        __syncthreads();
    }

    // ---- Phase 4: cross-wave context reduce ----
#pragma unroll
    for (int ct = 0; ct < 4; ct++)
#pragma unroll
        for (int r = 0; r < 4; r++)
            u.ctx[w][agrp * 4 + r][ct * 16 + arow] = cacc[ct][r];
    __syncthreads();

    float* ctx_b = ctx_out + ((size_t)b * SEQ + qbase) * AD;
    for (int i = t; i < 16 * 64; i += 256) {
        int r = i >> 6, a = i & 63;
        float v = u.ctx[0][r][a] + u.ctx[1][r][a] + u.ctx[2][r][a] + u.ctx[3][r][a];
        ctx_b[(size_t)r * AD + a] = v;
    }
}

// ---------------------------------------------------------------------------
extern "C" void kernel_launch(void* const* d_in, const int* in_sizes, int n_in,
                              void* d_out, int out_size, void* d_ws, size_t ws_size,
                              hipStream_t stream) {
    const float* q_in = (const float*)d_in[0];
    const float* k_in = (const float*)d_in[1];
    const float* v_in = (const float*)d_in[2];
    const float* Wq = (const float*)d_in[3];
    const float* bq = (const float*)d_in[4];
    const float* Wk = (const float*)d_in[5];
    const float* bk = (const float*)d_in[6];
    const float* Wv = (const float*)d_in[7];
    const float* bv = (const float*)d_in[8];

    unsigned short* q_bf = (unsigned short*)d_ws;                  // [8*2048][64]
    unsigned short* k_bf = q_bf + (size_t)NB * SEQ * AD;           // [8*2048][64]
    unsigned short* vT   = k_bf + (size_t)NB * SEQ * AD;           // [8][64][2048]
    unsigned short* wT   = vT + (size_t)NB * AD * SEQ;             // [3][64][1024]

    float* ctx_out = (float*)d_out;
    float* attn_out = ctx_out + (size_t)NB * SEQ * AD;

    hipLaunchKernelGGL(wT_kernel, dim3(16, 3), dim3(256), 0, stream, Wq, Wk, Wv, wT);
    hipLaunchKernelGGL(proj_kernel, dim3(256, 3), dim3(256), 0, stream,
                       q_in, k_in, v_in, bq, bk, bv, wT, q_bf, k_bf, vT);
    hipLaunchKernelGGL(attn_kernel, dim3(128, 8), dim3(256), 0, stream,
                       q_bf, k_bf, vT, ctx_out, attn_out);
}

// Round 3
// 176.238 us; speedup vs baseline: 1.1723x; 1.1723x over previous
//
#include <hip/hip_runtime.h>
#include <hip/hip_bf16.h>

#define NB 8
#define SEQ 2048
#define DM 1024
#define AD 64

// exp(s/32) = 2^(s * 0.03125 * log2(e));  log2(e)/32 = 0.045084220
#define SCL2 0.04508422f

typedef __attribute__((ext_vector_type(8))) short short8;
typedef __attribute__((ext_vector_type(4))) float f32x4;

static __device__ __forceinline__ unsigned short f2bf(float f) {
    unsigned int u = __float_as_uint(f);
    u += 0x7FFFu + ((u >> 16) & 1u);
    return (unsigned short)(u >> 16);
}

static __device__ __forceinline__ f32x4 mfma16(short8 a, short8 b, f32x4 c) {
    return __builtin_amdgcn_mfma_f32_16x16x32_bf16(a, b, c, 0, 0, 0);
}

static __device__ __forceinline__ short8 pack8(float4 a, float4 b) {
    short8 r;
    r[0] = (short)f2bf(a.x); r[1] = (short)f2bf(a.y);
    r[2] = (short)f2bf(a.z); r[3] = (short)f2bf(a.w);
    r[4] = (short)f2bf(b.x); r[5] = (short)f2bf(b.y);
    r[6] = (short)f2bf(b.z); r[7] = (short)f2bf(b.w);
    return r;
}

// ---------------------------------------------------------------------------
// Kernel 0: transpose + convert W (fp32 [1024][64]) -> wT bf16 [3][64][1024]
// ---------------------------------------------------------------------------
__global__ __launch_bounds__(256) void wT_kernel(
    const float* __restrict__ Wq, const float* __restrict__ Wk,
    const float* __restrict__ Wv, unsigned short* __restrict__ wT) {
    int p = blockIdx.y;
    int k0 = blockIdx.x * 64;
    const float* W = (p == 0) ? Wq : (p == 1) ? Wk : Wv;
    __shared__ unsigned short tl[64][72];
    int t = threadIdx.x;
    int c = t & 63;
    int r0 = t >> 6;
    for (int i = 0; i < 16; i++) {
        int k = r0 + i * 4;
        tl[c][k] = f2bf(W[(size_t)(k0 + k) * AD + c]);
    }
    __syncthreads();
    for (int i = 0; i < 16; i++) {
        int a = r0 + i * 4;
        wT[((size_t)p * AD + a) * DM + k0 + c] = tl[a][c];
    }
}

// ---------------------------------------------------------------------------
// Kernel 1: projection X[16384][1024] @ W[1024][64] + b -> bf16.
// Register-direct: each X element is consumed by exactly one lane, so no LDS
// staging, no barriers in the K-loop.
// grid (256, 3), block 256 (wave w owns rows w*16..w*16+15).
// ---------------------------------------------------------------------------
__global__ __launch_bounds__(256) void proj_kernel(
    const float* __restrict__ q_in, const float* __restrict__ k_in,
    const float* __restrict__ v_in, const float* __restrict__ bq,
    const float* __restrict__ bk, const float* __restrict__ bv,
    const unsigned short* __restrict__ wT,
    unsigned short* __restrict__ q_out, unsigned short* __restrict__ k_out,
    unsigned short* __restrict__ vT_out) {
    int p = blockIdx.y;
    int rbase = blockIdx.x * 64;
    const float* X = (p == 0) ? q_in : (p == 1) ? k_in : v_in;
    const float* bias = (p == 0) ? bq : (p == 1) ? bk : bv;
    const unsigned short* wTp = wT + (size_t)p * AD * DM;

    __shared__ unsigned short x_lds[64][72];  // only used in p==2 epilogue

    int t = threadIdx.x;
    int lane = t & 63;
    int w = t >> 6;
    int arow = lane & 15;
    int agrp = lane >> 4;

    const float* Xr = X + (size_t)(rbase + w * 16 + arow) * DM;

    f32x4 acc[4];
#pragma unroll
    for (int ct = 0; ct < 4; ct++) acc[ct] = (f32x4){0.f, 0.f, 0.f, 0.f};

    for (int ks = 0; ks < 16; ++ks) {
        int kb = ks * 64;
        float4 x0 = *reinterpret_cast<const float4*>(&Xr[kb + agrp * 8]);
        float4 x1 = *reinterpret_cast<const float4*>(&Xr[kb + agrp * 8 + 4]);
        float4 x2 = *reinterpret_cast<const float4*>(&Xr[kb + 32 + agrp * 8]);
        float4 x3 = *reinterpret_cast<const float4*>(&Xr[kb + 32 + agrp * 8 + 4]);
        short8 af0 = pack8(x0, x1);
        short8 af1 = pack8(x2, x3);
#pragma unroll
        for (int ct = 0; ct < 4; ct++) {
            const unsigned short* wr = wTp + (size_t)(ct * 16 + arow) * DM + kb;
            short8 bf0 = *reinterpret_cast<const short8*>(wr + agrp * 8);
            short8 bf1 = *reinterpret_cast<const short8*>(wr + 32 + agrp * 8);
            acc[ct] = mfma16(af0, bf0, acc[ct]);
            acc[ct] = mfma16(af1, bf1, acc[ct]);
        }
    }

    if (p < 2) {
        unsigned short* outp = (p == 0) ? q_out : k_out;
#pragma unroll
        for (int ct = 0; ct < 4; ct++) {
            int a = ct * 16 + arow;
            float bv_ = bias[a];
#pragma unroll
            for (int r = 0; r < 4; r++) {
                int row = rbase + w * 16 + agrp * 4 + r;
                outp[(size_t)row * AD + a] = f2bf(acc[ct][r] + bv_);
            }
        }
    } else {
        // transpose tile via LDS, then write vT[b][a][s]
#pragma unroll
        for (int ct = 0; ct < 4; ct++) {
            int a = ct * 16 + arow;
            float bv_ = bias[a];
#pragma unroll
            for (int r = 0; r < 4; r++) {
                int row = w * 16 + agrp * 4 + r;
                x_lds[a][row] = f2bf(acc[ct][r] + bv_);
            }
        }
        __syncthreads();
        int bidx = rbase >> 11;
        int sbase = rbase & 2047;
        int rr = t & 63;
        for (int i = 0; i < 16; i++) {
            int a = (t >> 6) + i * 4;
            vT_out[((size_t)bidx * AD + a) * SEQ + sbase + rr] = x_lds[a][rr];
        }
    }
}

// ---------------------------------------------------------------------------
// Kernel 2: attention, two-pass, no score tile in LDS.
// Pass A: QK^T -> row sums of exp (no max subtraction; |s| <= ~4, fp32-safe).
// Pass B: recompute QK^T, normalize via exp2(s*c - log2(sum)), write attn
//         from registers, stage bf16 P chunk (64 keys) in LDS, PV MFMA.
// grid (128, 8), block 256 (4 waves; wave w owns keys [w*512,(w+1)*512)).
// ---------------------------------------------------------------------------
__global__ __launch_bounds__(256, 4) void attn_kernel(
    const unsigned short* __restrict__ qb, const unsigned short* __restrict__ kb,
    const unsigned short* __restrict__ vT, float* __restrict__ ctx_out,
    float* __restrict__ attn_out) {
    int b = blockIdx.y;
    int qbase = blockIdx.x * 16;

    __shared__ float wsum[4][16];
    __shared__ float lr_lds[16];
    // 64 keys/chunk + pad: row stride 72 shorts = 144 B (9x16B, b128-aligned).
    // (Round-2 bug: this was [48] -> rows aliased -> PV read clobbered data.)
    __shared__ unsigned short p_lds[4][16][72];
    __shared__ float ctx_lds[4][16][68];

    int t = threadIdx.x;
    int lane = t & 63;
    int w = t >> 6;
    int arow = lane & 15;
    int agrp = lane >> 4;

    const unsigned short* qrow = qb + ((size_t)b * SEQ + qbase) * AD;
    short8 qf0 = *reinterpret_cast<const short8*>(qrow + (size_t)arow * AD + agrp * 8);
    short8 qf1 = *reinterpret_cast<const short8*>(qrow + (size_t)arow * AD + 32 + agrp * 8);
    const unsigned short* kbp = kb + (size_t)b * SEQ * AD;

    // ---- Pass A: row sums of exp(score) ----
    float s[4] = {0.f, 0.f, 0.f, 0.f};
    for (int kt = 0; kt < 32; ++kt) {
        int key0 = w * 512 + kt * 16;
        const unsigned short* krow = kbp + (size_t)(key0 + arow) * AD;
        short8 kf0 = *reinterpret_cast<const short8*>(krow + agrp * 8);
        short8 kf1 = *reinterpret_cast<const short8*>(krow + 32 + agrp * 8);
        f32x4 acc = (f32x4){0.f, 0.f, 0.f, 0.f};
        acc = mfma16(qf0, kf0, acc);
        acc = mfma16(qf1, kf1, acc);
#pragma unroll
        for (int r = 0; r < 4; r++) s[r] += __builtin_amdgcn_exp2f(acc[r] * SCL2);
    }
#pragma unroll
    for (int r = 0; r < 4; r++) {
        s[r] += __shfl_xor(s[r], 1);
        s[r] += __shfl_xor(s[r], 2);
        s[r] += __shfl_xor(s[r], 4);
        s[r] += __shfl_xor(s[r], 8);
    }
    if (arow == 0) {
#pragma unroll
        for (int r = 0; r < 4; r++) wsum[w][agrp * 4 + r] = s[r];
    }
    __syncthreads();
    if (t < 16)
        lr_lds[t] = -__builtin_amdgcn_logf(wsum[0][t] + wsum[1][t] + wsum[2][t] + wsum[3][t]);
    __syncthreads();
    float lr[4];
#pragma unroll
    for (int r = 0; r < 4; r++) lr[r] = lr_lds[agrp * 4 + r];

    // ---- Pass B: recompute, normalize, write attn, PV ----
    float* attn_b = attn_out + ((size_t)b * SEQ + qbase) * SEQ;
    const unsigned short* vTb = vT + (size_t)b * AD * SEQ;
    f32x4 cacc[4];
#pragma unroll
    for (int ct = 0; ct < 4; ct++) cacc[ct] = (f32x4){0.f, 0.f, 0.f, 0.f};

    for (int c8 = 0; c8 < 8; ++c8) {
        int key0b = w * 512 + c8 * 64;
#pragma unroll
        for (int kb4 = 0; kb4 < 4; ++kb4) {
            int k0 = key0b + kb4 * 16;
            const unsigned short* krow = kbp + (size_t)(k0 + arow) * AD;
            short8 kf0 = *reinterpret_cast<const short8*>(krow + agrp * 8);
            short8 kf1 = *reinterpret_cast<const short8*>(krow + 32 + agrp * 8);
            f32x4 acc = (f32x4){0.f, 0.f, 0.f, 0.f};
            acc = mfma16(qf0, kf0, acc);
            acc = mfma16(qf1, kf1, acc);
#pragma unroll
            for (int r = 0; r < 4; r++) {
                float e = __builtin_amdgcn_exp2f(acc[r] * SCL2 + lr[r]);
                attn_b[(size_t)(agrp * 4 + r) * SEQ + k0 + arow] = e;
                p_lds[w][agrp * 4 + r][kb4 * 16 + arow] = f2bf(e);
            }
        }
        __syncthreads();
#pragma unroll
        for (int ks = 0; ks < 2; ++ks) {
            short8 pf = *reinterpret_cast<const short8*>(&p_lds[w][arow][ks * 32 + agrp * 8]);
#pragma unroll
            for (int ct = 0; ct < 4; ct++) {
                const unsigned short* vr =
                    vTb + (size_t)(ct * 16 + arow) * SEQ + key0b + ks * 32 + agrp * 8;
                cacc[ct] = mfma16(pf, *reinterpret_cast<const short8*>(vr), cacc[ct]);
            }
        }
        __syncthreads();
    }

    // ---- cross-wave context reduce ----
#pragma unroll
    for (int ct = 0; ct < 4; ct++)
#pragma unroll
        for (int r = 0; r < 4; r++)
            ctx_lds[w][agrp * 4 + r][ct * 16 + arow] = cacc[ct][r];
    __syncthreads();

    float* ctx_b = ctx_out + ((size_t)b * SEQ + qbase) * AD;
    for (int i = t; i < 16 * 64; i += 256) {
        int r = i >> 6, a = i & 63;
        float v = ctx_lds[0][r][a] + ctx_lds[1][r][a] + ctx_lds[2][r][a] + ctx_lds[3][r][a];
        ctx_b[(size_t)r * AD + a] = v;
    }
}

// ---------------------------------------------------------------------------
extern "C" void kernel_launch(void* const* d_in, const int* in_sizes, int n_in,
                              void* d_out, int out_size, void* d_ws, size_t ws_size,
                              hipStream_t stream) {
    const float* q_in = (const float*)d_in[0];
    const float* k_in = (const float*)d_in[1];
    const float* v_in = (const float*)d_in[2];
    const float* Wq = (const float*)d_in[3];
    const float* bq = (const float*)d_in[4];
    const float* Wk = (const float*)d_in[5];
    const float* bk = (const float*)d_in[6];
    const float* Wv = (const float*)d_in[7];
    const float* bv = (const float*)d_in[8];

    unsigned short* q_bf = (unsigned short*)d_ws;                  // [8*2048][64]
    unsigned short* k_bf = q_bf + (size_t)NB * SEQ * AD;           // [8*2048][64]
    unsigned short* vT   = k_bf + (size_t)NB * SEQ * AD;           // [8][64][2048]
    unsigned short* wT   = vT + (size_t)NB * AD * SEQ;             // [3][64][1024]

    float* ctx_out = (float*)d_out;
    float* attn_out = ctx_out + (size_t)NB * SEQ * AD;

    hipLaunchKernelGGL(wT_kernel, dim3(16, 3), dim3(256), 0, stream, Wq, Wk, Wv, wT);
    hipLaunchKernelGGL(proj_kernel, dim3(256, 3), dim3(256), 0, stream,
                       q_in, k_in, v_in, bq, bk, bv, wT, q_bf, k_bf, vT);
    hipLaunchKernelGGL(attn_kernel, dim3(128, 8), dim3(256), 0, stream,
                       q_bf, k_bf, vT, ctx_out, attn_out);
}

// Round 4
// 167.262 us; speedup vs baseline: 1.2353x; 1.0537x over previous
//
#include <hip/hip_runtime.h>
#include <hip/hip_bf16.h>

#define NB 8
#define SEQ 2048
#define DM 1024
#define AD 64

// exp(s/32) = 2^(s * 0.03125 * log2(e));  log2(e)/32 = 0.045084220
#define SCL2 0.04508422f

typedef __attribute__((ext_vector_type(8))) short short8;
typedef __attribute__((ext_vector_type(4))) float f32x4;

static __device__ __forceinline__ unsigned short f2bf(float f) {
    unsigned int u = __float_as_uint(f);
    u += 0x7FFFu + ((u >> 16) & 1u);
    return (unsigned short)(u >> 16);
}

static __device__ __forceinline__ f32x4 mfma16(short8 a, short8 b, f32x4 c) {
    return __builtin_amdgcn_mfma_f32_16x16x32_bf16(a, b, c, 0, 0, 0);
}

static __device__ __forceinline__ short8 pack8(float4 a, float4 b) {
    short8 r;
    r[0] = (short)f2bf(a.x); r[1] = (short)f2bf(a.y);
    r[2] = (short)f2bf(a.z); r[3] = (short)f2bf(a.w);
    r[4] = (short)f2bf(b.x); r[5] = (short)f2bf(b.y);
    r[6] = (short)f2bf(b.z); r[7] = (short)f2bf(b.w);
    return r;
}

// ---------------------------------------------------------------------------
// Kernel 0: transpose + convert W (fp32 [1024][64]) -> wT bf16 [3][64][1024]
// ---------------------------------------------------------------------------
__global__ __launch_bounds__(256) void wT_kernel(
    const float* __restrict__ Wq, const float* __restrict__ Wk,
    const float* __restrict__ Wv, unsigned short* __restrict__ wT) {
    int p = blockIdx.y;
    int k0 = blockIdx.x * 64;
    const float* W = (p == 0) ? Wq : (p == 1) ? Wk : Wv;
    __shared__ unsigned short tl[64][72];
    int t = threadIdx.x;
    int c = t & 63;
    int r0 = t >> 6;
    for (int i = 0; i < 16; i++) {
        int k = r0 + i * 4;
        tl[c][k] = f2bf(W[(size_t)(k0 + k) * AD + c]);
    }
    __syncthreads();
    for (int i = 0; i < 16; i++) {
        int a = r0 + i * 4;
        wT[((size_t)p * AD + a) * DM + k0 + c] = tl[a][c];
    }
}

// ---------------------------------------------------------------------------
// Kernel 1: projection X[16384][1024] @ W[1024][64] + b -> bf16.
// Register-direct with explicit 1-deep prefetch of the next X K-slice so HBM
// latency overlaps compute. No barriers in the K-loop.
// grid (256, 3), block 256 (wave w owns rows w*16..w*16+15).
// ---------------------------------------------------------------------------
__global__ __launch_bounds__(256) void proj_kernel(
    const float* __restrict__ q_in, const float* __restrict__ k_in,
    const float* __restrict__ v_in, const float* __restrict__ bq,
    const float* __restrict__ bk, const float* __restrict__ bv,
    const unsigned short* __restrict__ wT,
    unsigned short* __restrict__ q_out, unsigned short* __restrict__ k_out,
    unsigned short* __restrict__ vT_out) {
    int p = blockIdx.y;
    int rbase = blockIdx.x * 64;
    const float* X = (p == 0) ? q_in : (p == 1) ? k_in : v_in;
    const float* bias = (p == 0) ? bq : (p == 1) ? bk : bv;
    const unsigned short* wTp = wT + (size_t)p * AD * DM;

    __shared__ unsigned short x_lds[64][72];  // only used in p==2 epilogue

    int t = threadIdx.x;
    int lane = t & 63;
    int w = t >> 6;
    int arow = lane & 15;
    int agrp = lane >> 4;

    const float* Xr = X + (size_t)(rbase + w * 16 + arow) * DM + agrp * 8;

    f32x4 acc[4];
#pragma unroll
    for (int ct = 0; ct < 4; ct++) acc[ct] = (f32x4){0.f, 0.f, 0.f, 0.f};

    float4 nx0 = *reinterpret_cast<const float4*>(Xr + 0);
    float4 nx1 = *reinterpret_cast<const float4*>(Xr + 4);
    float4 nx2 = *reinterpret_cast<const float4*>(Xr + 32);
    float4 nx3 = *reinterpret_cast<const float4*>(Xr + 36);

#pragma unroll
    for (int ks = 0; ks < 16; ++ks) {
        int kb = ks * 64;
        float4 x0 = nx0, x1 = nx1, x2 = nx2, x3 = nx3;
        if (ks < 15) {
            const float* Xn = Xr + (ks + 1) * 64;
            nx0 = *reinterpret_cast<const float4*>(Xn + 0);
            nx1 = *reinterpret_cast<const float4*>(Xn + 4);
            nx2 = *reinterpret_cast<const float4*>(Xn + 32);
            nx3 = *reinterpret_cast<const float4*>(Xn + 36);
        }
        short8 af0 = pack8(x0, x1);
        short8 af1 = pack8(x2, x3);
#pragma unroll
        for (int ct = 0; ct < 4; ct++) {
            const unsigned short* wr = wTp + (size_t)(ct * 16 + arow) * DM + kb;
            short8 bf0 = *reinterpret_cast<const short8*>(wr + agrp * 8);
            short8 bf1 = *reinterpret_cast<const short8*>(wr + 32 + agrp * 8);
            acc[ct] = mfma16(af0, bf0, acc[ct]);
            acc[ct] = mfma16(af1, bf1, acc[ct]);
        }
    }

    if (p < 2) {
        unsigned short* outp = (p == 0) ? q_out : k_out;
#pragma unroll
        for (int ct = 0; ct < 4; ct++) {
            int a = ct * 16 + arow;
            float bv_ = bias[a];
#pragma unroll
            for (int r = 0; r < 4; r++) {
                int row = rbase + w * 16 + agrp * 4 + r;
                outp[(size_t)row * AD + a] = f2bf(acc[ct][r] + bv_);
            }
        }
    } else {
        // transpose tile via LDS, then write vT[b][a][s]
#pragma unroll
        for (int ct = 0; ct < 4; ct++) {
            int a = ct * 16 + arow;
            float bv_ = bias[a];
#pragma unroll
            for (int r = 0; r < 4; r++) {
                int row = w * 16 + agrp * 4 + r;
                x_lds[a][row] = f2bf(acc[ct][r] + bv_);
            }
        }
        __syncthreads();
        int bidx = rbase >> 11;
        int sbase = rbase & 2047;
        int rr = t & 63;
        for (int i = 0; i < 16; i++) {
            int a = (t >> 6) + i * 4;
            vT_out[((size_t)bidx * AD + a) * SEQ + sbase + rr] = x_lds[a][rr];
        }
    }
}

// ---------------------------------------------------------------------------
// Kernel 2: attention, two-pass, no score tile in LDS.
// Flat grid 1024: b = blk & 7 pins each batch to one XCD, so that batch's
// K (2 MB) + vT (2 MB) stay L2-resident; attn/ctx stores are nontemporal so
// the 135 MB write stream doesn't evict them.
// Pass B is barrier-free: p_lds is wave-private (per-wave LDS ordering is
// handled by lgkmcnt), so the compiler can pipeline across 64-key chunks.
// ---------------------------------------------------------------------------
__global__ __launch_bounds__(256, 4) void attn_kernel(
    const unsigned short* __restrict__ qb, const unsigned short* __restrict__ kb,
    const unsigned short* __restrict__ vT, float* __restrict__ ctx_out,
    float* __restrict__ attn_out) {
    int blk = blockIdx.x;
    int b = blk & 7;            // batch == XCD id
    int qbase = (blk >> 3) * 16;

    __shared__ float wsum[4][16];
    __shared__ float lr_lds[16];
    // 64 keys/chunk; row stride 72 shorts = 144 B (9x16B, b128-aligned).
    __shared__ unsigned short p_lds[4][16][72];
    __shared__ float ctx_lds[4][16][68];

    int t = threadIdx.x;
    int lane = t & 63;
    int w = t >> 6;
    int arow = lane & 15;
    int agrp = lane >> 4;

    const unsigned short* qrow = qb + ((size_t)b * SEQ + qbase) * AD;
    short8 qf0 = *reinterpret_cast<const short8*>(qrow + (size_t)arow * AD + agrp * 8);
    short8 qf1 = *reinterpret_cast<const short8*>(qrow + (size_t)arow * AD + 32 + agrp * 8);
    const unsigned short* kbp = kb + (size_t)b * SEQ * AD;

    // ---- Pass A: row sums of exp(score) ----
    float s[4] = {0.f, 0.f, 0.f, 0.f};
    for (int kt = 0; kt < 32; ++kt) {
        int key0 = w * 512 + kt * 16;
        const unsigned short* krow = kbp + (size_t)(key0 + arow) * AD;
        short8 kf0 = *reinterpret_cast<const short8*>(krow + agrp * 8);
        short8 kf1 = *reinterpret_cast<const short8*>(krow + 32 + agrp * 8);
        f32x4 acc = (f32x4){0.f, 0.f, 0.f, 0.f};
        acc = mfma16(qf0, kf0, acc);
        acc = mfma16(qf1, kf1, acc);
#pragma unroll
        for (int r = 0; r < 4; r++) s[r] += __builtin_amdgcn_exp2f(acc[r] * SCL2);
    }
#pragma unroll
    for (int r = 0; r < 4; r++) {
        s[r] += __shfl_xor(s[r], 1);
        s[r] += __shfl_xor(s[r], 2);
        s[r] += __shfl_xor(s[r], 4);
        s[r] += __shfl_xor(s[r], 8);
    }
    if (arow == 0) {
#pragma unroll
        for (int r = 0; r < 4; r++) wsum[w][agrp * 4 + r] = s[r];
    }
    __syncthreads();
    if (t < 16)
        lr_lds[t] = -__builtin_amdgcn_logf(wsum[0][t] + wsum[1][t] + wsum[2][t] + wsum[3][t]);
    __syncthreads();
    float lr[4];
#pragma unroll
    for (int r = 0; r < 4; r++) lr[r] = lr_lds[agrp * 4 + r];

    // ---- Pass B: recompute, normalize, write attn (nontemporal), PV ----
    float* attn_b = attn_out + ((size_t)b * SEQ + qbase) * SEQ;
    const unsigned short* vTb = vT + (size_t)b * AD * SEQ;
    f32x4 cacc[4];
#pragma unroll
    for (int ct = 0; ct < 4; ct++) cacc[ct] = (f32x4){0.f, 0.f, 0.f, 0.f};

    for (int c8 = 0; c8 < 8; ++c8) {
        int key0b = w * 512 + c8 * 64;
#pragma unroll
        for (int kb4 = 0; kb4 < 4; ++kb4) {
            int k0 = key0b + kb4 * 16;
            const unsigned short* krow = kbp + (size_t)(k0 + arow) * AD;
            short8 kf0 = *reinterpret_cast<const short8*>(krow + agrp * 8);
            short8 kf1 = *reinterpret_cast<const short8*>(krow + 32 + agrp * 8);
            f32x4 acc = (f32x4){0.f, 0.f, 0.f, 0.f};
            acc = mfma16(qf0, kf0, acc);
            acc = mfma16(qf1, kf1, acc);
#pragma unroll
            for (int r = 0; r < 4; r++) {
                float e = __builtin_amdgcn_exp2f(acc[r] * SCL2 + lr[r]);
                __builtin_nontemporal_store(
                    e, &attn_b[(size_t)(agrp * 4 + r) * SEQ + k0 + arow]);
                p_lds[w][agrp * 4 + r][kb4 * 16 + arow] = f2bf(e);
            }
        }
        // p_lds[w] is wave-private: no __syncthreads needed (lgkmcnt orders
        // this wave's LDS write->read). Lets loads/stores pipeline across c8.
#pragma unroll
        for (int ks = 0; ks < 2; ++ks) {
            short8 pf = *reinterpret_cast<const short8*>(&p_lds[w][arow][ks * 32 + agrp * 8]);
#pragma unroll
            for (int ct = 0; ct < 4; ct++) {
                const unsigned short* vr =
                    vTb + (size_t)(ct * 16 + arow) * SEQ + key0b + ks * 32 + agrp * 8;
                cacc[ct] = mfma16(pf, *reinterpret_cast<const short8*>(vr), cacc[ct]);
            }
        }
    }

    // ---- cross-wave context reduce ----
#pragma unroll
    for (int ct = 0; ct < 4; ct++)
#pragma unroll
        for (int r = 0; r < 4; r++)
            ctx_lds[w][agrp * 4 + r][ct * 16 + arow] = cacc[ct][r];
    __syncthreads();

    float* ctx_b = ctx_out + ((size_t)b * SEQ + qbase) * AD;
    for (int i = t; i < 16 * 64; i += 256) {
        int r = i >> 6, a = i & 63;
        float v = ctx_lds[0][r][a] + ctx_lds[1][r][a] + ctx_lds[2][r][a] + ctx_lds[3][r][a];
        __builtin_nontemporal_store(v, &ctx_b[(size_t)r * AD + a]);
    }
}

// ---------------------------------------------------------------------------
extern "C" void kernel_launch(void* const* d_in, const int* in_sizes, int n_in,
                              void* d_out, int out_size, void* d_ws, size_t ws_size,
                              hipStream_t stream) {
    const float* q_in = (const float*)d_in[0];
    const float* k_in = (const float*)d_in[1];
    const float* v_in = (const float*)d_in[2];
    const float* Wq = (const float*)d_in[3];
    const float* bq = (const float*)d_in[4];
    const float* Wk = (const float*)d_in[5];
    const float* bk = (const float*)d_in[6];
    const float* Wv = (const float*)d_in[7];
    const float* bv = (const float*)d_in[8];

    unsigned short* q_bf = (unsigned short*)d_ws;                  // [8*2048][64]
    unsigned short* k_bf = q_bf + (size_t)NB * SEQ * AD;           // [8*2048][64]
    unsigned short* vT   = k_bf + (size_t)NB * SEQ * AD;           // [8][64][2048]
    unsigned short* wT   = vT + (size_t)NB * AD * SEQ;             // [3][64][1024]

    float* ctx_out = (float*)d_out;
    float* attn_out = ctx_out + (size_t)NB * SEQ * AD;

    hipLaunchKernelGGL(wT_kernel, dim3(16, 3), dim3(256), 0, stream, Wq, Wk, Wv, wT);
    hipLaunchKernelGGL(proj_kernel, dim3(256, 3), dim3(256), 0, stream,
                       q_in, k_in, v_in, bq, bk, bv, wT, q_bf, k_bf, vT);
    hipLaunchKernelGGL(attn_kernel, dim3(1024), dim3(256), 0, stream,
                       q_bf, k_bf, vT, ctx_out, attn_out);
}